// Round 2
// baseline (438.849 us; speedup 1.0000x reference)
//
#include <hip/hip_runtime.h>
#include <math.h>

#define NUMPIX 256
#define NUMBIN 367
#define NUMTHETA 360
#define NS 4
#define NT 367
#define NPIX2 (NUMPIX * NUMPIX)          // 65536
#define NRAYS_ALL (NUMTHETA * NUMBIN)    // 132120
#define NANG_SUB (NUMTHETA / NS)         // 90
#define NRAYS_SUB (NANG_SUB * NUMBIN)    // 33030

// 180-degree mirror symmetry: FP[a+180][b] == FP[a][366-b] exactly (same
// bilinear sample points, reversed t order; t-grid is symmetric). All ray
// marches (Minv, subset FP, residual FP) compute only angles [0,180) and
// emit both the ray and its mirror. 180 % NS == 0 so each subset pairs up
// internally (subset-local row k <-> k+45).
#define NANG_HALF 180
#define NRAYS_HALF (NANG_HALF * NUMBIN)      // 66060
#define NANG_SUBH (NANG_SUB / 2)             // 45
#define NRAYS_SUBH (NANG_SUBH * NUMBIN)      // 16515

#define CDET 183.0f
#define CPIX 127.5f
#define TOFF 183.0f                      // (NT-1)/2
#define DEN_EPS 1e-6f
#define EPS_F 2.2204460492503131e-16f    // float64 eps
#define RES2_THRESH 1e-4f                // (0.01)^2
#define INV_DINV (1.0f / 90.0f)          // backproject(ones) == 90 exactly

// quad-interleaved image: element (r,c) = float2(img[r][c], img[r+1][c])
// rows r in [-1,256] stored at +1 (258 rows), cols c in [-1,258] at +1
// Pixel (py,px) value lives at Qf[(py+1)*QW+px+1].x (also .y of the row
// above) — canonical fk storage. NOTE: sampling clamps coords to [-1,256];
// the clamp is the TAIL MASK for overshoot lanes of the rounded-up chunk
// loop. Do NOT remove it (round-8 failure). Grid-wide-sync fusion abandoned
// (r10/r11: co-residency not reliable on this part) — dispatch-count cuts
// below use only stream-order + device-scope atomics instead.
#define QW 260                           // float2 stride
#define QROWS 258
#define QN2 (QW * QROWS)                 // 67080 float2
#define QNF (QN2 * 2)                    // 134160 floats

// exact-cover grids: 4 rays/wave, 4 waves/block -> 16 rays/block
#define HALF_BLOCKS ((NRAYS_HALF + 15) / 16)   // 4129 (residual FP + Minv)
#define SUBH_BLOCKS ((NRAYS_SUBH + 15) / 16)   // 1033 (subset FP)

typedef float f4q __attribute__((ext_vector_type(4), aligned(8)));
typedef float f2u __attribute__((ext_vector_type(2), aligned(4)));

// ---- workspace layout (in floats) ----
#define OFF_COS   0
#define OFF_SIN   (OFF_COS + NUMTHETA)           // 360
#define OFF_MINV  (OFF_SIN + NUMTHETA)           // 720
#define OFF_RES   (OFF_MINV + NRAYS_ALL)         // res1, res2, counter, pad
#define OFF_Q     (OFF_RES + 8)                  // even-aligned
#define OFF_QT    (OFF_Q + QNF)
#define OFF_Q0    (OFF_QT + QNF)                 // pristine f0 quads (cold path)
#define OFF_QT0   (OFF_Q0 + QNF)
#define OFF_DIFF  (OFF_QT0 + QNF)                // diffs A [90,367]
#define OFF_DIFFB (OFF_DIFF + NRAYS_SUB + 2)     // diffs B (from f0; cold path)

// generic t-interval clip: keep c0 + rate*tt within (bLo, bHi)
__device__ __forceinline__ void clip_axis2(float c0, float rate,
                                           float bLo, float bHi,
                                           float& lo, float& hi) {
    if (fabsf(rate) > 1e-6f) {
        float inv = 1.0f / rate;
        float a = (bLo - c0) * inv;
        float b = (bHi - c0) * inv;
        lo = fmaxf(lo, fminf(a, b));
        hi = fminf(hi, fmaxf(a, b));
    } else if (c0 <= bLo || c0 >= bHi) {
        lo = 1e9f; hi = -1e9f;
    }
}

// sampled t-range in 16-sample chunks; coords stay within clamp range
__device__ __forceinline__ int ray_chunks16(float x0, float y0, float ca, float sa,
                                            int& itlo) {
    float lo = -1e9f, hi = 1e9f;
    clip_axis2(x0, -sa, -2.0f, 257.0f, lo, hi);
    clip_axis2(y0,  ca, -2.0f, 257.0f, lo, hi);
    if (hi < lo) { itlo = 0; return 0; }
    int a = (int)floorf(lo + TOFF) - 1; if (a < 0) a = 0;
    int b = (int)ceilf(hi + TOFF) + 1;  if (b > NT - 1) b = NT - 1;
    itlo = a;
    if (b < a) return 0;
    return (b - a + 16) >> 4;
}

struct RaySetup {
    int angle, bin, ai, nc;
    float u, v, du, dv;
    bool useT;
};

__device__ __forceinline__ RaySetup ray_setup(int rr, int angleStart, int angleStride,
                                              const float* __restrict__ cosA,
                                              const float* __restrict__ sinA,
                                              int slane) {
    RaySetup R;
    R.ai = rr / NUMBIN;
    R.bin = rr - R.ai * NUMBIN;
    R.angle = angleStart + R.ai * angleStride;    // always < 180
    float ca = cosA[R.angle], sa = sinA[R.angle];
    float s = (float)R.bin - CDET;
    float x0 = fmaf(s, ca, CPIX);             // x(tt) = x0 - tt*sa
    float y0 = fmaf(s, sa, CPIX);             // y(tt) = y0 + tt*ca
    int itlo;
    R.nc = ray_chunks16(x0, y0, ca, sa, itlo);
    R.useT = fabsf(ca) > fabsf(sa);           // uniform per sub-group
    float u0 = R.useT ? y0 : x0, du = R.useT ? ca : -sa;   // fast (contiguous)
    float v0 = R.useT ? x0 : y0, dv = R.useT ? -sa : ca;   // slow (strided)
    float tt0 = (float)(itlo + slane) - TOFF;
    R.u = fmaf(tt0, du, u0);
    R.v = fmaf(tt0, dv, v0);
    R.du = du; R.dv = dv;
    return R;
}

// chunk loop unrolled x2, dual accumulators; DUAL also samples imgB at the
// same addresses (shared coord/addr math — the cold-branch image).
template <bool DUAL>
__device__ __forceinline__ void march(const float* __restrict__ imgA,
                                      const float* __restrict__ imgB,
                                      float u, float v, float du, float dv,
                                      int nc, float& outA, float& outB) {
    const float du16 = du * 16.0f, dv16 = dv * 16.0f;
    const float du32 = du * 32.0f, dv32 = dv * 32.0f;
    float a0 = 0.0f, a1 = 0.0f, b0 = 0.0f, b1 = 0.0f;
    int ic = 0;
    for (; ic + 1 < nc; ic += 2) {
        float u1 = fminf(fmaxf(u, -1.0f), 256.0f);
        float v1 = fminf(fmaxf(v, -1.0f), 256.0f);
        float u2 = fminf(fmaxf(u + du16, -1.0f), 256.0f);
        float v2 = fminf(fmaxf(v + dv16, -1.0f), 256.0f);
        float fu1 = floorf(u1), fv1 = floorf(v1);
        float fu2 = floorf(u2), fv2 = floorf(v2);
        float wu1 = u1 - fu1, wv1 = v1 - fv1;
        float wu2 = u2 - fu2, wv2 = v2 - fv2;
        int idx1 = (int)fmaf(fv1, (float)QW, fu1);
        int idx2 = (int)fmaf(fv2, (float)QW, fu2);
        f4q qa1 = *(const f4q*)(imgA + idx1 * 2);
        f4q qa2 = *(const f4q*)(imgA + idx2 * 2);
        float t1 = fmaf(wu1, qa1.z - qa1.x, qa1.x);
        float c1 = fmaf(wu1, qa1.w - qa1.y, qa1.y);
        a0 += fmaf(wv1, c1 - t1, t1);
        float t2 = fmaf(wu2, qa2.z - qa2.x, qa2.x);
        float c2 = fmaf(wu2, qa2.w - qa2.y, qa2.y);
        a1 += fmaf(wv2, c2 - t2, t2);
        if (DUAL) {
            f4q qb1 = *(const f4q*)(imgB + idx1 * 2);
            f4q qb2 = *(const f4q*)(imgB + idx2 * 2);
            float s1 = fmaf(wu1, qb1.z - qb1.x, qb1.x);
            float d1 = fmaf(wu1, qb1.w - qb1.y, qb1.y);
            b0 += fmaf(wv1, d1 - s1, s1);
            float s2 = fmaf(wu2, qb2.z - qb2.x, qb2.x);
            float d2 = fmaf(wu2, qb2.w - qb2.y, qb2.y);
            b1 += fmaf(wv2, d2 - s2, s2);
        }
        u += du32; v += dv32;
    }
    if (ic < nc) {
        float u1 = fminf(fmaxf(u, -1.0f), 256.0f);
        float v1 = fminf(fmaxf(v, -1.0f), 256.0f);
        float fu1 = floorf(u1), fv1 = floorf(v1);
        float wu1 = u1 - fu1, wv1 = v1 - fv1;
        int idx1 = (int)fmaf(fv1, (float)QW, fu1);
        f4q qa1 = *(const f4q*)(imgA + idx1 * 2);
        float t1 = fmaf(wu1, qa1.z - qa1.x, qa1.x);
        float c1 = fmaf(wu1, qa1.w - qa1.y, qa1.y);
        a0 += fmaf(wv1, c1 - t1, t1);
        if (DUAL) {
            f4q qb1 = *(const f4q*)(imgB + idx1 * 2);
            float s1 = fmaf(wu1, qb1.z - qb1.x, qb1.x);
            float d1 = fmaf(wu1, qb1.w - qb1.y, qb1.y);
            b0 += fmaf(wv1, d1 - s1, s1);
        }
    }
    outA = a0 + a1;
    outB = b0 + b1;
}

// ---------------- init + Minv in one dispatch ----------------
// Also builds the pristine f0 quads (Q0/QT0) used by the cold (res1<=thr)
// branch after select#1 was folded away.
__global__ __launch_bounds__(256)
void init_minv_kernel(float* __restrict__ cosA, float* __restrict__ sinA,
                      float* __restrict__ Qf, float* __restrict__ QTf,
                      float* __restrict__ Q0f, float* __restrict__ QT0f,
                      float* __restrict__ minv,
                      const float* __restrict__ f0) {
    int idx = blockIdx.x * blockDim.x + threadIdx.x;
    if (idx < NUMTHETA) {
        float th = (float)((double)idx * 0.017453292519943295);
        cosA[idx] = (float)cos((double)th);
        sinA[idx] = (float)sin((double)th);
    }
    if (idx < QN2) {
        int qr = idx / QW, qc = idx - qr * QW;
        int r = qr - 1, c = qc - 1;                 // r in [-1,256], c in [-1,258]
        bool cv = ((unsigned)c < 256u);
        bool rv0 = ((unsigned)r < 256u), rv1 = ((unsigned)(r + 1) < 256u);
        float a = (cv && rv0) ? f0[r * NUMPIX + c] : 0.0f;
        float b = (cv && rv1) ? f0[(r + 1) * NUMPIX + c] : 0.0f;
        Qf[idx * 2] = a;  Qf[idx * 2 + 1] = b;
        Q0f[idx * 2] = a; Q0f[idx * 2 + 1] = b;
        // transposed image: imgT(r,c) = f0[c][r]
        float ta = (cv && rv0) ? f0[c * NUMPIX + r] : 0.0f;
        float tb = (cv && rv1) ? f0[c * NUMPIX + (r + 1)] : 0.0f;
        QTf[idx * 2] = ta;  QTf[idx * 2 + 1] = tb;
        QT0f[idx * 2] = ta; QT0f[idx * 2 + 1] = tb;
    }

    // ---- Minv portion: 16 lanes per ray, 4 rays/wave, 16 rays/block.
    // Own per-ray trig via __sincosf (normalizer only; ~1e-6 rel, far under
    // threshold). Angles [0,180) only; mirror gets the identical value.
    const int lane = threadIdx.x & 63;
    const int wid = threadIdx.x >> 6;
    const int sub = lane >> 4, slane = lane & 15;
    int ray = blockIdx.x * 16 + wid * 4 + sub;
    if (ray >= NRAYS_HALF) return;           // whole 16-lane group exits
    int angle = ray / NUMBIN;                // angle in [0,180)
    int bin = ray - angle * NUMBIN;
    float th = (float)((double)angle * 0.017453292519943295);
    float ca, sa;
    __sincosf(th, &sa, &ca);
    float s = (float)bin - CDET;
    float x0 = fmaf(s, ca, CPIX);                 // x(tt) = x0 - tt*sa
    float y0 = fmaf(s, sa, CPIX);                 // y(tt) = y0 + tt*ca
    float acc = 0.0f;
    int count = 0;
    float lo = -1e9f, hi = 1e9f;
    clip_axis2(x0, -sa, -2.0f, 257.0f, lo, hi);
    clip_axis2(y0,  ca, -2.0f, 257.0f, lo, hi);
    int e1a = 0, e1b = -1, e2a = 0, e2b = -1;
    if (hi >= lo) {
        int itA = (int)floorf(lo + TOFF) - 1; if (itA < 0) itA = 0;
        int itB = (int)ceilf(hi + TOFF) + 1;  if (itB > NT - 1) itB = NT - 1;
        if (itB >= itA) {
            // strict interior: both coords in (0.05, 254.95) -> weight exactly 1
            float ilo = -1e9f, ihi = 1e9f;
            clip_axis2(x0, -sa, 0.05f, 254.95f, ilo, ihi);
            clip_axis2(y0,  ca, 0.05f, 254.95f, ilo, ihi);
            int jA = 1, jB = 0;
            if (ihi >= ilo) {
                jA = (int)ceilf(ilo + TOFF) + 1;
                jB = (int)floorf(ihi + TOFF) - 1;
                if (jA < itA) jA = itA;
                if (jB > itB) jB = itB;
            }
            if (jB >= jA) {
                count = jB - jA + 1;
                e1a = itA; e1b = jA - 1;
                e2a = jB + 1; e2b = itB;
            } else {
                e1a = itA; e1b = itB;       // no interior: one full edge loop
            }
        }
    }
    #pragma unroll 1
    for (int base = e1a; base <= e1b; base += 16) {
        int t = base + slane;
        float tt = (float)t - TOFF;
        float x = fmaf(-tt, sa, x0);
        float y = fmaf(tt, ca, y0);
        float fx = floorf(x), fy = floorf(y);
        float wx = x - fx, wy = y - fy;
        int c0 = (int)fx, r0 = (int)fy;
        float ux = (((unsigned)c0 < 256u) ? (1.0f - wx) : 0.0f) +
                   (((unsigned)(c0 + 1) < 256u) ? wx : 0.0f);
        float uy = (((unsigned)r0 < 256u) ? (1.0f - wy) : 0.0f) +
                   (((unsigned)(r0 + 1) < 256u) ? wy : 0.0f);
        if (t <= e1b) acc += ux * uy;
    }
    #pragma unroll 1
    for (int base = e2a; base <= e2b; base += 16) {
        int t = base + slane;
        float tt = (float)t - TOFF;
        float x = fmaf(-tt, sa, x0);
        float y = fmaf(tt, ca, y0);
        float fx = floorf(x), fy = floorf(y);
        float wx = x - fx, wy = y - fy;
        int c0 = (int)fx, r0 = (int)fy;
        float ux = (((unsigned)c0 < 256u) ? (1.0f - wx) : 0.0f) +
                   (((unsigned)(c0 + 1) < 256u) ? wx : 0.0f);
        float uy = (((unsigned)r0 < 256u) ? (1.0f - wy) : 0.0f) +
                   (((unsigned)(r0 + 1) < 256u) ? wy : 0.0f);
        if (t <= e2b) acc += ux * uy;
    }
    acc += __shfl_down(acc, 8, 16);
    acc += __shfl_down(acc, 4, 16);
    acc += __shfl_down(acc, 2, 16);
    acc += __shfl_down(acc, 1, 16);
    if (slane == 0) {
        float m = fmaxf(acc + (float)count, DEN_EPS);
        minv[angle * NUMBIN + bin] = m;
        minv[(angle + NANG_HALF) * NUMBIN + (NUMBIN - 1 - bin)] = m;
    }
}

// residual block-unit: marches 16 half-rays of fk, returns block partial of
// sum over (base + mirror) squared diffs. All threads return the total.
__device__ __forceinline__ float res_block_partial(
        int unit, const float* __restrict__ Qn, const float* __restrict__ Qt,
        const float* __restrict__ sino,
        const float* __restrict__ cosA, const float* __restrict__ sinA,
        float* partLds) {
    const int wid = threadIdx.x >> 6, lane = threadIdx.x & 63;
    const int sub = lane >> 4, slane = lane & 15;
    int ray = unit * 16 + wid * 4 + sub;
    bool valid = ray < NRAYS_HALF;
    int rr = valid ? ray : NRAYS_HALF - 1;
    RaySetup R = ray_setup(rr, 0, 1, cosA, sinA, slane);
    const float* img = (R.useT ? Qt : Qn) + (QW + 1) * 2;
    float acc, dum;
    march<false>(img, img, R.u, R.v, R.du, R.dv, valid ? R.nc : 0, acc, dum);
    acc += __shfl_down(acc, 8, 16);
    acc += __shfl_down(acc, 4, 16);
    acc += __shfl_down(acc, 2, 16);
    acc += __shfl_down(acc, 1, 16);
    float d2 = 0.0f;
    if (slane == 0 && valid) {
        float d = acc - sino[R.angle * NUMBIN + R.bin];
        int a2 = R.angle + NANG_HALF;
        int b2 = NUMBIN - 1 - R.bin;
        float dm = acc - sino[a2 * NUMBIN + b2];
        d2 = d * d + dm * dm;
    }
    d2 += __shfl_down(d2, 16);
    d2 += __shfl_down(d2, 32);
    if (lane == 0) partLds[wid] = d2;
    __syncthreads();
    return partLds[0] + partLds[1] + partLds[2] + partLds[3];
}

// ---------------- subset forward projection (diffs) ----------------
__global__ __launch_bounds__(256)
void fp_sub_kernel(const float* __restrict__ Qn, const float* __restrict__ Qt,
                   const float* __restrict__ sino, const float* __restrict__ minv,
                   float* __restrict__ gOut,
                   const float* __restrict__ cosA, const float* __restrict__ sinA,
                   int j) {
    const int wid = threadIdx.x >> 6, lane = threadIdx.x & 63;
    const int sub = lane >> 4, slane = lane & 15;
    int ray = blockIdx.x * 16 + wid * 4 + sub;
    bool valid = ray < NRAYS_SUBH;
    int rr = valid ? ray : NRAYS_SUBH - 1;
    RaySetup R = ray_setup(rr, j, NS, cosA, sinA, slane);
    const float* img = (R.useT ? Qt : Qn) + (QW + 1) * 2;
    float acc, dum;
    march<false>(img, img, R.u, R.v, R.du, R.dv, valid ? R.nc : 0, acc, dum);
    acc += __shfl_down(acc, 8, 16);
    acc += __shfl_down(acc, 4, 16);
    acc += __shfl_down(acc, 2, 16);
    acc += __shfl_down(acc, 1, 16);
    if (slane == 0 && valid) {
        gOut[R.ai * NUMBIN + R.bin] =
            (sino[R.angle * NUMBIN + R.bin] - acc) /
            minv[R.angle * NUMBIN + R.bin];
        int a2 = R.angle + NANG_HALF;
        int b2 = NUMBIN - 1 - R.bin;
        gOut[(R.ai + NANG_SUBH) * NUMBIN + b2] =
            (sino[a2 * NUMBIN + b2] - acc) /
            minv[a2 * NUMBIN + b2];
    }
}

// ---------------- merged: residual(fk1)->res1 + subset-0 dual FP ---------
// Both parts read the same image state (fk1); independent of each other, so
// one dispatch saves a boundary. Subset part marches Qf AND Q0 (shared
// addresses) and writes both diff variants; bp(iter2,j=0) picks by res1.
__global__ __launch_bounds__(256)
void fp_merged_kernel(const float* __restrict__ Qn, const float* __restrict__ Qt,
                      const float* __restrict__ Q0n, const float* __restrict__ Q0t,
                      const float* __restrict__ sino, const float* __restrict__ minv,
                      float* __restrict__ gA, float* __restrict__ gB,
                      const float* __restrict__ cosA, const float* __restrict__ sinA,
                      float* __restrict__ resbuf) {
    __shared__ float part[4];
    int bid = blockIdx.x;
    if (bid < HALF_BLOCKS) {
        float tot = res_block_partial(bid, Qn, Qt, sino, cosA, sinA, part);
        if (threadIdx.x == 0) atomicAdd(&resbuf[0], tot);
        return;
    }
    int bid2 = bid - HALF_BLOCKS;
    const int wid = threadIdx.x >> 6, lane = threadIdx.x & 63;
    const int sub = lane >> 4, slane = lane & 15;
    int ray = bid2 * 16 + wid * 4 + sub;
    bool valid = ray < NRAYS_SUBH;
    int rr = valid ? ray : NRAYS_SUBH - 1;
    RaySetup R = ray_setup(rr, 0, NS, cosA, sinA, slane);   // j = 0
    const float* imgA = (R.useT ? Qt : Qn) + (QW + 1) * 2;
    const float* imgB = (R.useT ? Q0t : Q0n) + (QW + 1) * 2;
    float accA, accB;
    march<true>(imgA, imgB, R.u, R.v, R.du, R.dv, valid ? R.nc : 0, accA, accB);
    accA += __shfl_down(accA, 8, 16);
    accB += __shfl_down(accB, 8, 16);
    accA += __shfl_down(accA, 4, 16);
    accB += __shfl_down(accB, 4, 16);
    accA += __shfl_down(accA, 2, 16);
    accB += __shfl_down(accB, 2, 16);
    accA += __shfl_down(accA, 1, 16);
    accB += __shfl_down(accB, 1, 16);
    if (slane == 0 && valid) {
        float m1 = minv[R.angle * NUMBIN + R.bin];
        float s1 = sino[R.angle * NUMBIN + R.bin];
        gA[R.ai * NUMBIN + R.bin] = (s1 - accA) / m1;
        gB[R.ai * NUMBIN + R.bin] = (s1 - accB) / m1;
        int a2 = R.angle + NANG_HALF;
        int b2 = NUMBIN - 1 - R.bin;
        float m2 = minv[a2 * NUMBIN + b2];
        float s2 = sino[a2 * NUMBIN + b2];
        gA[(R.ai + NANG_SUBH) * NUMBIN + b2] = (s2 - accA) / m2;
        gB[(R.ai + NANG_SUBH) * NUMBIN + b2] = (s2 - accB) / m2;
    }
}

// ---------------- final: residual(fk2)->res2 + last-block select ---------
// Last block (threadfence + ticket) reads res1/res2 coherently (atomic RMW)
// and writes the output: f2 = res2>thr ? fk2 : (res1>thr ? fk1 : f0).
// fcur holds fk1 (written by bp(iter1,j=3)); fk2 is QA canonical.
__global__ __launch_bounds__(256)
void fp_final_kernel(const float* __restrict__ Qn, const float* __restrict__ Qt,
                     const float* __restrict__ sino,
                     const float* __restrict__ cosA, const float* __restrict__ sinA,
                     float* __restrict__ resbuf,
                     float* __restrict__ fcur, const float* __restrict__ f0) {
    __shared__ float part[4];
    __shared__ int lastFlag;
    float tot = res_block_partial(blockIdx.x, Qn, Qt, sino, cosA, sinA, part);
    if (threadIdx.x == 0) {
        atomicAdd(&resbuf[1], tot);
        __threadfence();
        unsigned old = atomicAdd((unsigned*)resbuf + 2, 1u);
        lastFlag = (old == (unsigned)(gridDim.x - 1)) ? 1 : 0;
    }
    __syncthreads();
    if (!lastFlag) return;
    float r2 = atomicAdd(&resbuf[1], 0.0f);    // coherent read (same dispatch)
    float r1 = atomicAdd(&resbuf[0], 0.0f);
    bool upd2 = r2 > RES2_THRESH;
    bool upd1 = r1 > RES2_THRESH;
    const int tid = threadIdx.x;
    #pragma unroll 4
    for (int p = tid; p < NPIX2; p += 256) {
        int px = p & (NUMPIX - 1), py = p >> 8;
        float v = upd2 ? Qn[((py + 1) * QW + (px + 1)) * 2]
                       : (upd1 ? fcur[p] : f0[p]);
        fcur[p] = v;
    }
}

// ---------------- backprojection + SART update ----------------
// Mirror-paired: angles a and a+180 share the sd chain (sd2 = 366 - sd;
// value2 = w*g2[365-i0] + (1-w)*g2[366-i0]; i0 in [2,363] so in-bounds).
// chooseFlag: pick {gA,Qf} vs {gB,Q0f} by res1 (cold branch of folded
// select#1). zeroSel: in-graph zeroing of the NEXT residual accumulator.
__global__ __launch_bounds__(256)
void bp_update_kernel(float* __restrict__ Qf, float* __restrict__ QTf,
                      const float* __restrict__ Q0f,
                      const float* __restrict__ gA, const float* __restrict__ gB,
                      const float* __restrict__ cosA, const float* __restrict__ sinA,
                      float* __restrict__ resbuf, float* __restrict__ fcur,
                      int j, int doClamp, int writeFcur, int chooseFlag,
                      int zeroSel) {
    __shared__ float part[4][64];
    if (zeroSel && blockIdx.x == 0 && threadIdx.x == 0) {
        if (zeroSel == 1) {
            resbuf[0] = 0.0f;
        } else {
            resbuf[1] = 0.0f;
            ((unsigned*)resbuf)[2] = 0u;
        }
    }
    const float* g = gA;
    const float* src = Qf;
    if (chooseFlag && !(resbuf[0] > RES2_THRESH)) { g = gB; src = Q0f; }
    const int tx = threadIdx.x & 63;
    const int ty = threadIdx.x >> 6;
    int p = blockIdx.x * 64 + tx;
    int px = p & (NUMPIX - 1), py = p >> 8;
    float X = (float)px - CPIX, Y = (float)py - CPIX;
    float acc = 0.0f;
    for (int i = ty; i < NANG_SUBH; i += 4) {
        int angle = j + NS * i;
        float ca = cosA[angle], sa = sinA[angle];
        float sd = fmaf(X, ca, fmaf(Y, sa, CDET));   // always in [2.7, 363.3]
        float fl = floorf(sd);
        float w = sd - fl;
        int i0 = (int)fl;
        f2u gv = *(const f2u*)(g + i * NUMBIN + i0);
        acc += fmaf(w, gv.y - gv.x, gv.x);
        // mirror angle (a+180): sd2 = 366 - sd
        f2u gw = *(const f2u*)(g + (i + NANG_SUBH) * NUMBIN + (365 - i0));
        acc += fmaf(w, gw.x - gw.y, gw.y);
    }
    part[ty][tx] = acc;
    __syncthreads();
    if (ty == 0) {
        float s = part[0][tx] + part[1][tx] + part[2][tx] + part[3][tx];
        float bp = (fabsf(s) > 1000.0f) ? 0.0f : s;
        float v = src[((py + 1) * QW + (px + 1)) * 2] + bp * INV_DINV;
        if (doClamp) v = fmaxf(v, EPS_F);
        // quad-image updates: pixel (py,px) lives in 2 elements per layout
        Qf[((py + 1) * QW + (px + 1)) * 2]      = v;
        Qf[(py * QW + (px + 1)) * 2 + 1]        = v;
        QTf[((px + 1) * QW + (py + 1)) * 2]     = v;
        QTf[(px * QW + (py + 1)) * 2 + 1]       = v;
        if (writeFcur) fcur[p] = v;               // fk1 snapshot (hot-path f1)
    }
}

extern "C" void kernel_launch(void* const* d_in, const int* in_sizes, int n_in,
                              void* d_out, int out_size, void* d_ws, size_t ws_size,
                              hipStream_t stream) {
    const float* f0 = (const float*)d_in[0];     // [256,256]
    const float* sino = (const float*)d_in[1];   // [360,367]
    float* fcur = (float*)d_out;                 // [256,256] output "f"
    float* ws = (float*)d_ws;

    float* cosA = ws + OFF_COS;
    float* sinA = ws + OFF_SIN;
    float* minv = ws + OFF_MINV;   // [360,367] indexed by global angle
    float* resb = ws + OFF_RES;    // res1, res2, counter
    float* Qf   = ws + OFF_Q;      // quad image (normal) — canonical fk store
    float* QTf  = ws + OFF_QT;     // quad image (transposed)
    float* Q0f  = ws + OFF_Q0;     // pristine f0 quads (cold branch)
    float* QT0f = ws + OFF_QT0;
    float* dfA  = ws + OFF_DIFF;   // diffs from fk
    float* dfB  = ws + OFF_DIFFB;  // diffs from f0 (cold branch)

    // 18 dispatches total (was 21): select#1 folded into bp/fp via res1
    // flag; fp2#1 merged with fp1(iter2,j=0); select#2 folded into fp2#2
    // via last-block reduction.
    init_minv_kernel<<<HALF_BLOCKS, 256, 0, stream>>>(
        cosA, sinA, Qf, QTf, Q0f, QT0f, minv, f0);

    // ---- iteration 1 ----
    for (int j = 0; j < NS; j++) {
        fp_sub_kernel<<<SUBH_BLOCKS, 256, 0, stream>>>(
            Qf, QTf, sino, minv, dfA, cosA, sinA, j);
        bp_update_kernel<<<NPIX2 / 64, 256, 0, stream>>>(
            Qf, QTf, Q0f, dfA, dfB, cosA, sinA, resb, fcur,
            j, (j == NS - 1) ? 1 : 0, (j == NS - 1) ? 1 : 0, 0,
            (j == NS - 1) ? 1 : 0);
    }
    // ---- iteration boundary: residual(fk1) + subset-0 dual FP ----
    fp_merged_kernel<<<HALF_BLOCKS + SUBH_BLOCKS, 256, 0, stream>>>(
        Qf, QTf, Q0f, QT0f, sino, minv, dfA, dfB, cosA, sinA, resb);
    bp_update_kernel<<<NPIX2 / 64, 256, 0, stream>>>(
        Qf, QTf, Q0f, dfA, dfB, cosA, sinA, resb, fcur,
        0, 0, 0, 1, 0);
    // ---- iteration 2, subsets 1..3 ----
    for (int j = 1; j < NS; j++) {
        fp_sub_kernel<<<SUBH_BLOCKS, 256, 0, stream>>>(
            Qf, QTf, sino, minv, dfA, cosA, sinA, j);
        bp_update_kernel<<<NPIX2 / 64, 256, 0, stream>>>(
            Qf, QTf, Q0f, dfA, dfB, cosA, sinA, resb, fcur,
            j, (j == NS - 1) ? 1 : 0, 0, 0,
            (j == NS - 1) ? 2 : 0);
    }
    // ---- final residual + fused select ----
    fp_final_kernel<<<HALF_BLOCKS, 256, 0, stream>>>(
        Qf, QTf, sino, cosA, sinA, resb, fcur, f0);
}

// Round 3
// 428.784 us; speedup vs baseline: 1.0235x; 1.0235x over previous
//
#include <hip/hip_runtime.h>
#include <math.h>

#define NUMPIX 256
#define NUMBIN 367
#define NUMTHETA 360
#define NS 4
#define NT 367
#define NPIX2 (NUMPIX * NUMPIX)          // 65536
#define NRAYS_ALL (NUMTHETA * NUMBIN)    // 132120
#define NANG_SUB (NUMTHETA / NS)         // 90
#define NRAYS_SUB (NANG_SUB * NUMBIN)    // 33030

// 180-degree mirror symmetry: FP[a+180][b] == FP[a][366-b] exactly (same
// bilinear sample points, reversed t order; t-grid is symmetric). All ray
// marches (Minv, subset FP, residual FP) compute only angles [0,180) and
// emit both the ray and its mirror. 180 % NS == 0 so each subset pairs up
// internally (subset-local row k <-> k+45).
#define NANG_HALF 180
#define NRAYS_HALF (NANG_HALF * NUMBIN)      // 66060
#define NANG_SUBH (NANG_SUB / 2)             // 45
#define NRAYS_SUBH (NANG_SUBH * NUMBIN)      // 16515

#define CDET 183.0f
#define CPIX 127.5f
#define TOFF 183.0f                      // (NT-1)/2
#define DEN_EPS 1e-6f
#define EPS_F 2.2204460492503131e-16f    // float64 eps
#define RES2_THRESH 1e-4f                // (0.01)^2
#define INV_DINV (1.0f / 90.0f)          // backproject(ones) == 90 exactly

// quad-interleaved image: element (r,c) = float2(img[r][c], img[r+1][c])
// rows r in [-1,256] stored at +1 (258 rows), cols c in [-1,258] at +1
// Pixel (py,px) value lives at Qf[(py+1)*QW+px+1].x (also .y of the row
// above) — canonical fk storage. NOTE: sampling clamps coords to [-1,256];
// the clamp is the TAIL MASK for overshoot lanes of the rounded-up chunk
// loop. Do NOT remove it (round-8 failure). Grid-wide-sync fusion abandoned
// (r10/r11: co-residency not reliable on this part) — dispatch-count cuts
// use only stream-order + device-scope atomics.
// ROUND-2 LESSON: NEVER __threadfence() per block on this part — agent-scope
// release fence = per-XCD L2 writeback (L2s not cross-coherent) and 4129 of
// them cost ~160 µs. Atomic-atomic ordering needs only s_waitcnt vmcnt(0).
#define QW 260                           // float2 stride
#define QROWS 258
#define QN2 (QW * QROWS)                 // 67080 float2
#define QNF (QN2 * 2)                    // 134160 floats

// exact-cover grids: 4 rays/wave, 4 waves/block -> 16 rays/block
#define HALF_BLOCKS ((NRAYS_HALF + 15) / 16)   // 4129 (residual FP + Minv)
#define SUBH_BLOCKS ((NRAYS_SUBH + 15) / 16)   // 1033 (subset FP)

typedef float f4q __attribute__((ext_vector_type(4), aligned(8)));
typedef float f2u __attribute__((ext_vector_type(2), aligned(4)));

// ---- workspace layout (in floats) ----
#define OFF_COS   0
#define OFF_SIN   (OFF_COS + NUMTHETA)           // 360
#define OFF_MINV  (OFF_SIN + NUMTHETA)           // 720
#define OFF_RES   (OFF_MINV + NRAYS_ALL)         // res1, res2, counter, pad
#define OFF_Q     (OFF_RES + 8)                  // even-aligned
#define OFF_QT    (OFF_Q + QNF)
#define OFF_Q0    (OFF_QT + QNF)                 // pristine f0 quads (cold path)
#define OFF_QT0   (OFF_Q0 + QNF)
#define OFF_DIFF  (OFF_QT0 + QNF)                // diffs A [90,367]
#define OFF_DIFFB (OFF_DIFF + NRAYS_SUB + 2)     // diffs B (from f0; cold path)

// generic t-interval clip: keep c0 + rate*tt within (bLo, bHi)
__device__ __forceinline__ void clip_axis2(float c0, float rate,
                                           float bLo, float bHi,
                                           float& lo, float& hi) {
    if (fabsf(rate) > 1e-6f) {
        float inv = 1.0f / rate;
        float a = (bLo - c0) * inv;
        float b = (bHi - c0) * inv;
        lo = fmaxf(lo, fminf(a, b));
        hi = fminf(hi, fmaxf(a, b));
    } else if (c0 <= bLo || c0 >= bHi) {
        lo = 1e9f; hi = -1e9f;
    }
}

// sampled t-range in 16-sample chunks; coords stay within clamp range
__device__ __forceinline__ int ray_chunks16(float x0, float y0, float ca, float sa,
                                            int& itlo) {
    float lo = -1e9f, hi = 1e9f;
    clip_axis2(x0, -sa, -2.0f, 257.0f, lo, hi);
    clip_axis2(y0,  ca, -2.0f, 257.0f, lo, hi);
    if (hi < lo) { itlo = 0; return 0; }
    int a = (int)floorf(lo + TOFF) - 1; if (a < 0) a = 0;
    int b = (int)ceilf(hi + TOFF) + 1;  if (b > NT - 1) b = NT - 1;
    itlo = a;
    if (b < a) return 0;
    return (b - a + 16) >> 4;
}

struct RaySetup {
    int angle, bin, ai, nc;
    float u, v, du, dv;
    bool useT;
};

__device__ __forceinline__ RaySetup ray_setup(int rr, int angleStart, int angleStride,
                                              const float* __restrict__ cosA,
                                              const float* __restrict__ sinA,
                                              int slane) {
    RaySetup R;
    R.ai = rr / NUMBIN;
    R.bin = rr - R.ai * NUMBIN;
    R.angle = angleStart + R.ai * angleStride;    // always < 180
    float ca = cosA[R.angle], sa = sinA[R.angle];
    float s = (float)R.bin - CDET;
    float x0 = fmaf(s, ca, CPIX);             // x(tt) = x0 - tt*sa
    float y0 = fmaf(s, sa, CPIX);             // y(tt) = y0 + tt*ca
    int itlo;
    R.nc = ray_chunks16(x0, y0, ca, sa, itlo);
    R.useT = fabsf(ca) > fabsf(sa);           // uniform per sub-group
    float u0 = R.useT ? y0 : x0, du = R.useT ? ca : -sa;   // fast (contiguous)
    float v0 = R.useT ? x0 : y0, dv = R.useT ? -sa : ca;   // slow (strided)
    float tt0 = (float)(itlo + slane) - TOFF;
    R.u = fmaf(tt0, du, u0);
    R.v = fmaf(tt0, dv, v0);
    R.du = du; R.dv = dv;
    return R;
}

// chunk loop unrolled x2, dual accumulators; DUAL also samples imgB at the
// same addresses (shared coord/addr math — the cold-branch image).
template <bool DUAL>
__device__ __forceinline__ void march(const float* __restrict__ imgA,
                                      const float* __restrict__ imgB,
                                      float u, float v, float du, float dv,
                                      int nc, float& outA, float& outB) {
    const float du16 = du * 16.0f, dv16 = dv * 16.0f;
    const float du32 = du * 32.0f, dv32 = dv * 32.0f;
    float a0 = 0.0f, a1 = 0.0f, b0 = 0.0f, b1 = 0.0f;
    int ic = 0;
    for (; ic + 1 < nc; ic += 2) {
        float u1 = fminf(fmaxf(u, -1.0f), 256.0f);
        float v1 = fminf(fmaxf(v, -1.0f), 256.0f);
        float u2 = fminf(fmaxf(u + du16, -1.0f), 256.0f);
        float v2 = fminf(fmaxf(v + dv16, -1.0f), 256.0f);
        float fu1 = floorf(u1), fv1 = floorf(v1);
        float fu2 = floorf(u2), fv2 = floorf(v2);
        float wu1 = u1 - fu1, wv1 = v1 - fv1;
        float wu2 = u2 - fu2, wv2 = v2 - fv2;
        int idx1 = (int)fmaf(fv1, (float)QW, fu1);
        int idx2 = (int)fmaf(fv2, (float)QW, fu2);
        f4q qa1 = *(const f4q*)(imgA + idx1 * 2);
        f4q qa2 = *(const f4q*)(imgA + idx2 * 2);
        float t1 = fmaf(wu1, qa1.z - qa1.x, qa1.x);
        float c1 = fmaf(wu1, qa1.w - qa1.y, qa1.y);
        a0 += fmaf(wv1, c1 - t1, t1);
        float t2 = fmaf(wu2, qa2.z - qa2.x, qa2.x);
        float c2 = fmaf(wu2, qa2.w - qa2.y, qa2.y);
        a1 += fmaf(wv2, c2 - t2, t2);
        if (DUAL) {
            f4q qb1 = *(const f4q*)(imgB + idx1 * 2);
            f4q qb2 = *(const f4q*)(imgB + idx2 * 2);
            float s1 = fmaf(wu1, qb1.z - qb1.x, qb1.x);
            float d1 = fmaf(wu1, qb1.w - qb1.y, qb1.y);
            b0 += fmaf(wv1, d1 - s1, s1);
            float s2 = fmaf(wu2, qb2.z - qb2.x, qb2.x);
            float d2 = fmaf(wu2, qb2.w - qb2.y, qb2.y);
            b1 += fmaf(wv2, d2 - s2, s2);
        }
        u += du32; v += dv32;
    }
    if (ic < nc) {
        float u1 = fminf(fmaxf(u, -1.0f), 256.0f);
        float v1 = fminf(fmaxf(v, -1.0f), 256.0f);
        float fu1 = floorf(u1), fv1 = floorf(v1);
        float wu1 = u1 - fu1, wv1 = v1 - fv1;
        int idx1 = (int)fmaf(fv1, (float)QW, fu1);
        f4q qa1 = *(const f4q*)(imgA + idx1 * 2);
        float t1 = fmaf(wu1, qa1.z - qa1.x, qa1.x);
        float c1 = fmaf(wu1, qa1.w - qa1.y, qa1.y);
        a0 += fmaf(wv1, c1 - t1, t1);
        if (DUAL) {
            f4q qb1 = *(const f4q*)(imgB + idx1 * 2);
            float s1 = fmaf(wu1, qb1.z - qb1.x, qb1.x);
            float d1 = fmaf(wu1, qb1.w - qb1.y, qb1.y);
            b0 += fmaf(wv1, d1 - s1, s1);
        }
    }
    outA = a0 + a1;
    outB = b0 + b1;
}

// ---------------- init + Minv in one dispatch ----------------
// Also builds the pristine f0 quads (Q0/QT0) used by the cold (res1<=thr)
// branch after select#1 was folded away.
__global__ __launch_bounds__(256)
void init_minv_kernel(float* __restrict__ cosA, float* __restrict__ sinA,
                      float* __restrict__ Qf, float* __restrict__ QTf,
                      float* __restrict__ Q0f, float* __restrict__ QT0f,
                      float* __restrict__ minv,
                      const float* __restrict__ f0) {
    int idx = blockIdx.x * blockDim.x + threadIdx.x;
    if (idx < NUMTHETA) {
        float th = (float)((double)idx * 0.017453292519943295);
        cosA[idx] = (float)cos((double)th);
        sinA[idx] = (float)sin((double)th);
    }
    if (idx < QN2) {
        int qr = idx / QW, qc = idx - qr * QW;
        int r = qr - 1, c = qc - 1;                 // r in [-1,256], c in [-1,258]
        bool cv = ((unsigned)c < 256u);
        bool rv0 = ((unsigned)r < 256u), rv1 = ((unsigned)(r + 1) < 256u);
        float a = (cv && rv0) ? f0[r * NUMPIX + c] : 0.0f;
        float b = (cv && rv1) ? f0[(r + 1) * NUMPIX + c] : 0.0f;
        Qf[idx * 2] = a;  Qf[idx * 2 + 1] = b;
        Q0f[idx * 2] = a; Q0f[idx * 2 + 1] = b;
        // transposed image: imgT(r,c) = f0[c][r]
        float ta = (cv && rv0) ? f0[c * NUMPIX + r] : 0.0f;
        float tb = (cv && rv1) ? f0[c * NUMPIX + (r + 1)] : 0.0f;
        QTf[idx * 2] = ta;  QTf[idx * 2 + 1] = tb;
        QT0f[idx * 2] = ta; QT0f[idx * 2 + 1] = tb;
    }

    // ---- Minv portion: 16 lanes per ray, 4 rays/wave, 16 rays/block.
    // Own per-ray trig via __sincosf (normalizer only; ~1e-6 rel, far under
    // threshold). Angles [0,180) only; mirror gets the identical value.
    const int lane = threadIdx.x & 63;
    const int wid = threadIdx.x >> 6;
    const int sub = lane >> 4, slane = lane & 15;
    int ray = blockIdx.x * 16 + wid * 4 + sub;
    if (ray >= NRAYS_HALF) return;           // whole 16-lane group exits
    int angle = ray / NUMBIN;                // angle in [0,180)
    int bin = ray - angle * NUMBIN;
    float th = (float)((double)angle * 0.017453292519943295);
    float ca, sa;
    __sincosf(th, &sa, &ca);
    float s = (float)bin - CDET;
    float x0 = fmaf(s, ca, CPIX);                 // x(tt) = x0 - tt*sa
    float y0 = fmaf(s, sa, CPIX);                 // y(tt) = y0 + tt*ca
    float acc = 0.0f;
    int count = 0;
    float lo = -1e9f, hi = 1e9f;
    clip_axis2(x0, -sa, -2.0f, 257.0f, lo, hi);
    clip_axis2(y0,  ca, -2.0f, 257.0f, lo, hi);
    int e1a = 0, e1b = -1, e2a = 0, e2b = -1;
    if (hi >= lo) {
        int itA = (int)floorf(lo + TOFF) - 1; if (itA < 0) itA = 0;
        int itB = (int)ceilf(hi + TOFF) + 1;  if (itB > NT - 1) itB = NT - 1;
        if (itB >= itA) {
            // strict interior: both coords in (0.05, 254.95) -> weight exactly 1
            float ilo = -1e9f, ihi = 1e9f;
            clip_axis2(x0, -sa, 0.05f, 254.95f, ilo, ihi);
            clip_axis2(y0,  ca, 0.05f, 254.95f, ilo, ihi);
            int jA = 1, jB = 0;
            if (ihi >= ilo) {
                jA = (int)ceilf(ilo + TOFF) + 1;
                jB = (int)floorf(ihi + TOFF) - 1;
                if (jA < itA) jA = itA;
                if (jB > itB) jB = itB;
            }
            if (jB >= jA) {
                count = jB - jA + 1;
                e1a = itA; e1b = jA - 1;
                e2a = jB + 1; e2b = itB;
            } else {
                e1a = itA; e1b = itB;       // no interior: one full edge loop
            }
        }
    }
    #pragma unroll 1
    for (int base = e1a; base <= e1b; base += 16) {
        int t = base + slane;
        float tt = (float)t - TOFF;
        float x = fmaf(-tt, sa, x0);
        float y = fmaf(tt, ca, y0);
        float fx = floorf(x), fy = floorf(y);
        float wx = x - fx, wy = y - fy;
        int c0 = (int)fx, r0 = (int)fy;
        float ux = (((unsigned)c0 < 256u) ? (1.0f - wx) : 0.0f) +
                   (((unsigned)(c0 + 1) < 256u) ? wx : 0.0f);
        float uy = (((unsigned)r0 < 256u) ? (1.0f - wy) : 0.0f) +
                   (((unsigned)(r0 + 1) < 256u) ? wy : 0.0f);
        if (t <= e1b) acc += ux * uy;
    }
    #pragma unroll 1
    for (int base = e2a; base <= e2b; base += 16) {
        int t = base + slane;
        float tt = (float)t - TOFF;
        float x = fmaf(-tt, sa, x0);
        float y = fmaf(tt, ca, y0);
        float fx = floorf(x), fy = floorf(y);
        float wx = x - fx, wy = y - fy;
        int c0 = (int)fx, r0 = (int)fy;
        float ux = (((unsigned)c0 < 256u) ? (1.0f - wx) : 0.0f) +
                   (((unsigned)(c0 + 1) < 256u) ? wx : 0.0f);
        float uy = (((unsigned)r0 < 256u) ? (1.0f - wy) : 0.0f) +
                   (((unsigned)(r0 + 1) < 256u) ? wy : 0.0f);
        if (t <= e2b) acc += ux * uy;
    }
    acc += __shfl_down(acc, 8, 16);
    acc += __shfl_down(acc, 4, 16);
    acc += __shfl_down(acc, 2, 16);
    acc += __shfl_down(acc, 1, 16);
    if (slane == 0) {
        float m = fmaxf(acc + (float)count, DEN_EPS);
        minv[angle * NUMBIN + bin] = m;
        minv[(angle + NANG_HALF) * NUMBIN + (NUMBIN - 1 - bin)] = m;
    }
}

// residual block-unit: marches 16 half-rays of fk, returns block partial of
// sum over (base + mirror) squared diffs. All threads return the total.
__device__ __forceinline__ float res_block_partial(
        int unit, const float* __restrict__ Qn, const float* __restrict__ Qt,
        const float* __restrict__ sino,
        const float* __restrict__ cosA, const float* __restrict__ sinA,
        float* partLds) {
    const int wid = threadIdx.x >> 6, lane = threadIdx.x & 63;
    const int sub = lane >> 4, slane = lane & 15;
    int ray = unit * 16 + wid * 4 + sub;
    bool valid = ray < NRAYS_HALF;
    int rr = valid ? ray : NRAYS_HALF - 1;
    RaySetup R = ray_setup(rr, 0, 1, cosA, sinA, slane);
    const float* img = (R.useT ? Qt : Qn) + (QW + 1) * 2;
    float acc, dum;
    march<false>(img, img, R.u, R.v, R.du, R.dv, valid ? R.nc : 0, acc, dum);
    acc += __shfl_down(acc, 8, 16);
    acc += __shfl_down(acc, 4, 16);
    acc += __shfl_down(acc, 2, 16);
    acc += __shfl_down(acc, 1, 16);
    float d2 = 0.0f;
    if (slane == 0 && valid) {
        float d = acc - sino[R.angle * NUMBIN + R.bin];
        int a2 = R.angle + NANG_HALF;
        int b2 = NUMBIN - 1 - R.bin;
        float dm = acc - sino[a2 * NUMBIN + b2];
        d2 = d * d + dm * dm;
    }
    d2 += __shfl_down(d2, 16);
    d2 += __shfl_down(d2, 32);
    if (lane == 0) partLds[wid] = d2;
    __syncthreads();
    return partLds[0] + partLds[1] + partLds[2] + partLds[3];
}

// ---------------- subset forward projection (diffs) ----------------
__global__ __launch_bounds__(256)
void fp_sub_kernel(const float* __restrict__ Qn, const float* __restrict__ Qt,
                   const float* __restrict__ sino, const float* __restrict__ minv,
                   float* __restrict__ gOut,
                   const float* __restrict__ cosA, const float* __restrict__ sinA,
                   int j) {
    const int wid = threadIdx.x >> 6, lane = threadIdx.x & 63;
    const int sub = lane >> 4, slane = lane & 15;
    int ray = blockIdx.x * 16 + wid * 4 + sub;
    bool valid = ray < NRAYS_SUBH;
    int rr = valid ? ray : NRAYS_SUBH - 1;
    RaySetup R = ray_setup(rr, j, NS, cosA, sinA, slane);
    const float* img = (R.useT ? Qt : Qn) + (QW + 1) * 2;
    float acc, dum;
    march<false>(img, img, R.u, R.v, R.du, R.dv, valid ? R.nc : 0, acc, dum);
    acc += __shfl_down(acc, 8, 16);
    acc += __shfl_down(acc, 4, 16);
    acc += __shfl_down(acc, 2, 16);
    acc += __shfl_down(acc, 1, 16);
    if (slane == 0 && valid) {
        gOut[R.ai * NUMBIN + R.bin] =
            (sino[R.angle * NUMBIN + R.bin] - acc) /
            minv[R.angle * NUMBIN + R.bin];
        int a2 = R.angle + NANG_HALF;
        int b2 = NUMBIN - 1 - R.bin;
        gOut[(R.ai + NANG_SUBH) * NUMBIN + b2] =
            (sino[a2 * NUMBIN + b2] - acc) /
            minv[a2 * NUMBIN + b2];
    }
}

// ---------------- merged: residual(fk1)->res1 + subset-0 dual FP ---------
// Both parts read the same image state (fk1); independent of each other, so
// one dispatch saves a boundary. Subset part marches Qf AND Q0 (shared
// addresses) and writes both diff variants; bp(iter2,j=0) picks by res1.
__global__ __launch_bounds__(256)
void fp_merged_kernel(const float* __restrict__ Qn, const float* __restrict__ Qt,
                      const float* __restrict__ Q0n, const float* __restrict__ Q0t,
                      const float* __restrict__ sino, const float* __restrict__ minv,
                      float* __restrict__ gA, float* __restrict__ gB,
                      const float* __restrict__ cosA, const float* __restrict__ sinA,
                      float* __restrict__ resbuf) {
    __shared__ float part[4];
    int bid = blockIdx.x;
    if (bid < HALF_BLOCKS) {
        float tot = res_block_partial(bid, Qn, Qt, sino, cosA, sinA, part);
        if (threadIdx.x == 0) atomicAdd(&resbuf[0], tot);
        return;
    }
    int bid2 = bid - HALF_BLOCKS;
    const int wid = threadIdx.x >> 6, lane = threadIdx.x & 63;
    const int sub = lane >> 4, slane = lane & 15;
    int ray = bid2 * 16 + wid * 4 + sub;
    bool valid = ray < NRAYS_SUBH;
    int rr = valid ? ray : NRAYS_SUBH - 1;
    RaySetup R = ray_setup(rr, 0, NS, cosA, sinA, slane);   // j = 0
    const float* imgA = (R.useT ? Qt : Qn) + (QW + 1) * 2;
    const float* imgB = (R.useT ? Q0t : Q0n) + (QW + 1) * 2;
    float accA, accB;
    march<true>(imgA, imgB, R.u, R.v, R.du, R.dv, valid ? R.nc : 0, accA, accB);
    accA += __shfl_down(accA, 8, 16);
    accB += __shfl_down(accB, 8, 16);
    accA += __shfl_down(accA, 4, 16);
    accB += __shfl_down(accB, 4, 16);
    accA += __shfl_down(accA, 2, 16);
    accB += __shfl_down(accB, 2, 16);
    accA += __shfl_down(accA, 1, 16);
    accB += __shfl_down(accB, 1, 16);
    if (slane == 0 && valid) {
        float m1 = minv[R.angle * NUMBIN + R.bin];
        float s1 = sino[R.angle * NUMBIN + R.bin];
        gA[R.ai * NUMBIN + R.bin] = (s1 - accA) / m1;
        gB[R.ai * NUMBIN + R.bin] = (s1 - accB) / m1;
        int a2 = R.angle + NANG_HALF;
        int b2 = NUMBIN - 1 - R.bin;
        float m2 = minv[a2 * NUMBIN + b2];
        float s2 = sino[a2 * NUMBIN + b2];
        gA[(R.ai + NANG_SUBH) * NUMBIN + b2] = (s2 - accA) / m2;
        gB[(R.ai + NANG_SUBH) * NUMBIN + b2] = (s2 - accB) / m2;
    }
}

// ---------------- final: residual(fk2)->res2 + last-block select ---------
// Last block (ticket pattern) reads res1/res2 coherently (atomic RMW at the
// LLC) and writes the output: f2 = res2>thr ? fk2 : (res1>thr ? fk1 : f0).
// fcur holds fk1 (written by bp(iter1,j=3)); fk2 is Qf canonical.
// Ordering partial-atomic before ticket-atomic uses s_waitcnt vmcnt(0)
// ONLY — __threadfence() here cost 160 µs (r2: per-block L2 writeback on
// the non-cross-coherent 8-XCD L2s). Both atomics are agent-scope RMWs at
// the coherent LLC, so completion order is all that's required.
__global__ __launch_bounds__(256)
void fp_final_kernel(const float* __restrict__ Qn, const float* __restrict__ Qt,
                     const float* __restrict__ sino,
                     const float* __restrict__ cosA, const float* __restrict__ sinA,
                     float* __restrict__ resbuf,
                     float* __restrict__ fcur, const float* __restrict__ f0) {
    __shared__ float part[4];
    __shared__ int lastFlag;
    float tot = res_block_partial(blockIdx.x, Qn, Qt, sino, cosA, sinA, part);
    if (threadIdx.x == 0) {
        atomicAdd(&resbuf[1], tot);
        asm volatile("s_waitcnt vmcnt(0)" ::: "memory");   // NOT __threadfence
        unsigned old = atomicAdd((unsigned*)resbuf + 2, 1u);
        lastFlag = (old == (unsigned)(gridDim.x - 1)) ? 1 : 0;
    }
    __syncthreads();
    if (!lastFlag) return;
    float r2 = atomicAdd(&resbuf[1], 0.0f);    // coherent read (LLC RMW)
    float r1 = atomicAdd(&resbuf[0], 0.0f);
    bool upd2 = r2 > RES2_THRESH;
    bool upd1 = r1 > RES2_THRESH;
    const int tid = threadIdx.x;
    #pragma unroll 4
    for (int p = tid; p < NPIX2; p += 256) {
        int px = p & (NUMPIX - 1), py = p >> 8;
        float v = upd2 ? Qn[((py + 1) * QW + (px + 1)) * 2]
                       : (upd1 ? fcur[p] : f0[p]);
        fcur[p] = v;
    }
}

// ---------------- backprojection + SART update ----------------
// Mirror-paired: angles a and a+180 share the sd chain (sd2 = 366 - sd;
// value2 = w*g2[365-i0] + (1-w)*g2[366-i0]; i0 in [2,363] so in-bounds).
// chooseFlag: pick {gA,Qf} vs {gB,Q0f} by res1 (cold branch of folded
// select#1). zeroSel: in-graph zeroing of the NEXT residual accumulator.
__global__ __launch_bounds__(256)
void bp_update_kernel(float* __restrict__ Qf, float* __restrict__ QTf,
                      const float* __restrict__ Q0f,
                      const float* __restrict__ gA, const float* __restrict__ gB,
                      const float* __restrict__ cosA, const float* __restrict__ sinA,
                      float* __restrict__ resbuf, float* __restrict__ fcur,
                      int j, int doClamp, int writeFcur, int chooseFlag,
                      int zeroSel) {
    __shared__ float part[4][64];
    if (zeroSel && blockIdx.x == 0 && threadIdx.x == 0) {
        if (zeroSel == 1) {
            resbuf[0] = 0.0f;
        } else {
            resbuf[1] = 0.0f;
            ((unsigned*)resbuf)[2] = 0u;
        }
    }
    const float* g = gA;
    const float* src = Qf;
    if (chooseFlag && !(resbuf[0] > RES2_THRESH)) { g = gB; src = Q0f; }
    const int tx = threadIdx.x & 63;
    const int ty = threadIdx.x >> 6;
    int p = blockIdx.x * 64 + tx;
    int px = p & (NUMPIX - 1), py = p >> 8;
    float X = (float)px - CPIX, Y = (float)py - CPIX;
    float acc = 0.0f;
    for (int i = ty; i < NANG_SUBH; i += 4) {
        int angle = j + NS * i;
        float ca = cosA[angle], sa = sinA[angle];
        float sd = fmaf(X, ca, fmaf(Y, sa, CDET));   // always in [2.7, 363.3]
        float fl = floorf(sd);
        float w = sd - fl;
        int i0 = (int)fl;
        f2u gv = *(const f2u*)(g + i * NUMBIN + i0);
        acc += fmaf(w, gv.y - gv.x, gv.x);
        // mirror angle (a+180): sd2 = 366 - sd
        f2u gw = *(const f2u*)(g + (i + NANG_SUBH) * NUMBIN + (365 - i0));
        acc += fmaf(w, gw.x - gw.y, gw.y);
    }
    part[ty][tx] = acc;
    __syncthreads();
    if (ty == 0) {
        float s = part[0][tx] + part[1][tx] + part[2][tx] + part[3][tx];
        float bp = (fabsf(s) > 1000.0f) ? 0.0f : s;
        float v = src[((py + 1) * QW + (px + 1)) * 2] + bp * INV_DINV;
        if (doClamp) v = fmaxf(v, EPS_F);
        // quad-image updates: pixel (py,px) lives in 2 elements per layout
        Qf[((py + 1) * QW + (px + 1)) * 2]      = v;
        Qf[(py * QW + (px + 1)) * 2 + 1]        = v;
        QTf[((px + 1) * QW + (py + 1)) * 2]     = v;
        QTf[(px * QW + (py + 1)) * 2 + 1]       = v;
        if (writeFcur) fcur[p] = v;               // fk1 snapshot (hot-path f1)
    }
}

extern "C" void kernel_launch(void* const* d_in, const int* in_sizes, int n_in,
                              void* d_out, int out_size, void* d_ws, size_t ws_size,
                              hipStream_t stream) {
    const float* f0 = (const float*)d_in[0];     // [256,256]
    const float* sino = (const float*)d_in[1];   // [360,367]
    float* fcur = (float*)d_out;                 // [256,256] output "f"
    float* ws = (float*)d_ws;

    float* cosA = ws + OFF_COS;
    float* sinA = ws + OFF_SIN;
    float* minv = ws + OFF_MINV;   // [360,367] indexed by global angle
    float* resb = ws + OFF_RES;    // res1, res2, counter
    float* Qf   = ws + OFF_Q;      // quad image (normal) — canonical fk store
    float* QTf  = ws + OFF_QT;     // quad image (transposed)
    float* Q0f  = ws + OFF_Q0;     // pristine f0 quads (cold branch)
    float* QT0f = ws + OFF_QT0;
    float* dfA  = ws + OFF_DIFF;   // diffs from fk
    float* dfB  = ws + OFF_DIFFB;  // diffs from f0 (cold branch)

    // 18 dispatches total (was 21): select#1 folded into bp/fp via res1
    // flag; fp2#1 merged with fp1(iter2,j=0); select#2 folded into fp2#2
    // via last-block reduction.
    init_minv_kernel<<<HALF_BLOCKS, 256, 0, stream>>>(
        cosA, sinA, Qf, QTf, Q0f, QT0f, minv, f0);

    // ---- iteration 1 ----
    for (int j = 0; j < NS; j++) {
        fp_sub_kernel<<<SUBH_BLOCKS, 256, 0, stream>>>(
            Qf, QTf, sino, minv, dfA, cosA, sinA, j);
        bp_update_kernel<<<NPIX2 / 64, 256, 0, stream>>>(
            Qf, QTf, Q0f, dfA, dfB, cosA, sinA, resb, fcur,
            j, (j == NS - 1) ? 1 : 0, (j == NS - 1) ? 1 : 0, 0,
            (j == NS - 1) ? 1 : 0);
    }
    // ---- iteration boundary: residual(fk1) + subset-0 dual FP ----
    fp_merged_kernel<<<HALF_BLOCKS + SUBH_BLOCKS, 256, 0, stream>>>(
        Qf, QTf, Q0f, QT0f, sino, minv, dfA, dfB, cosA, sinA, resb);
    bp_update_kernel<<<NPIX2 / 64, 256, 0, stream>>>(
        Qf, QTf, Q0f, dfA, dfB, cosA, sinA, resb, fcur,
        0, 0, 0, 1, 0);
    // ---- iteration 2, subsets 1..3 ----
    for (int j = 1; j < NS; j++) {
        fp_sub_kernel<<<SUBH_BLOCKS, 256, 0, stream>>>(
            Qf, QTf, sino, minv, dfA, cosA, sinA, j);
        bp_update_kernel<<<NPIX2 / 64, 256, 0, stream>>>(
            Qf, QTf, Q0f, dfA, dfB, cosA, sinA, resb, fcur,
            j, (j == NS - 1) ? 1 : 0, 0, 0,
            (j == NS - 1) ? 2 : 0);
    }
    // ---- final residual + fused select ----
    fp_final_kernel<<<HALF_BLOCKS, 256, 0, stream>>>(
        Qf, QTf, sino, cosA, sinA, resb, fcur, f0);
}

// Round 4
// 232.787 us; speedup vs baseline: 1.8852x; 1.8420x over previous
//
#include <hip/hip_runtime.h>
#include <math.h>

#define NUMPIX 256
#define NUMBIN 367
#define NUMTHETA 360
#define NS 4
#define NT 367
#define NPIX2 (NUMPIX * NUMPIX)          // 65536
#define NRAYS_ALL (NUMTHETA * NUMBIN)    // 132120
#define NANG_SUB (NUMTHETA / NS)         // 90
#define NRAYS_SUB (NANG_SUB * NUMBIN)    // 33030

// 180-degree mirror symmetry: FP[a+180][b] == FP[a][366-b] exactly (same
// bilinear sample points, reversed t order; t-grid is symmetric). All ray
// marches (Minv, subset FP, residual FP) compute only angles [0,180) and
// emit both the ray and its mirror. 180 % NS == 0 so each subset pairs up
// internally (subset-local row k <-> k+45).
#define NANG_HALF 180
#define NRAYS_HALF (NANG_HALF * NUMBIN)      // 66060
#define NANG_SUBH (NANG_SUB / 2)             // 45
#define NRAYS_SUBH (NANG_SUBH * NUMBIN)      // 16515

#define CDET 183.0f
#define CPIX 127.5f
#define TOFF 183.0f                      // (NT-1)/2
#define DEN_EPS 1e-6f
#define EPS_F 2.2204460492503131e-16f    // float64 eps
#define RES2_THRESH 1e-4f                // (0.01)^2
#define INV_DINV (1.0f / 90.0f)          // backproject(ones) == 90 exactly

// quad-interleaved image: element (r,c) = float2(img[r][c], img[r+1][c])
// rows r in [-1,256] stored at +1 (258 rows), cols c in [-1,258] at +1
// Pixel (py,px) value lives at Qf[(py+1)*QW+px+1].x (also .y of the row
// above) — canonical fk storage. NOTE: sampling clamps coords to [-1,256];
// the clamp is the TAIL MASK for overshoot lanes of the rounded-up chunk
// loop. Do NOT remove it (round-8 failure). Grid-wide-sync fusion abandoned
// (r10/r11: co-residency not reliable on this part).
// ROUND-2/3 LESSON: NO per-block device atomics to a shared address on this
// part. 4129 blocks x atomicAdd to ONE cache line serialize at the coherent
// fabric at ~O(100ns) each => ~150 us pileup (fp_final r2/r3: 169/162 us at
// 6.7% VALUBusy). Fence-vs-vmcnt was an A/B dud (169->162): the atomics
// themselves are the cost. Use distinct-slot partials + consumer-side
// reduction (r1-proven) — plain stores, dispatch-boundary coherence.
#define QW 260                           // float2 stride
#define QROWS 258
#define QN2 (QW * QROWS)                 // 67080 float2
#define QNF (QN2 * 2)                    // 134160 floats

// exact-cover grids: 4 rays/wave, 4 waves/block -> 16 rays/block
#define HALF_BLOCKS ((NRAYS_HALF + 15) / 16)   // 4129 (residual FP + Minv)
#define SUBH_BLOCKS ((NRAYS_SUBH + 15) / 16)   // 1033 (subset FP)

typedef float f4q __attribute__((ext_vector_type(4), aligned(8)));
typedef float f2u __attribute__((ext_vector_type(2), aligned(4)));

// ---- workspace layout (in floats) ----
#define OFF_COS   0
#define OFF_SIN   (OFF_COS + NUMTHETA)           // 360
#define OFF_MINV  (OFF_SIN + NUMTHETA)           // 720
#define OFF_RESP1 (OFF_MINV + NRAYS_ALL)         // 4129 block partials (res1)
#define OFF_RESP2 (OFF_RESP1 + 4136)             // 4129 block partials (res2)
#define OFF_Q     (OFF_RESP2 + 4136)             // even-aligned
#define OFF_QT    (OFF_Q + QNF)
#define OFF_Q0    (OFF_QT + QNF)                 // pristine f0 quads (cold path)
#define OFF_QT0   (OFF_Q0 + QNF)
#define OFF_DIFF  (OFF_QT0 + QNF)                // diffs A [90,367]
#define OFF_DIFFB (OFF_DIFF + NRAYS_SUB + 2)     // diffs B (from f0; cold path)

// generic t-interval clip: keep c0 + rate*tt within (bLo, bHi)
__device__ __forceinline__ void clip_axis2(float c0, float rate,
                                           float bLo, float bHi,
                                           float& lo, float& hi) {
    if (fabsf(rate) > 1e-6f) {
        float inv = 1.0f / rate;
        float a = (bLo - c0) * inv;
        float b = (bHi - c0) * inv;
        lo = fmaxf(lo, fminf(a, b));
        hi = fminf(hi, fmaxf(a, b));
    } else if (c0 <= bLo || c0 >= bHi) {
        lo = 1e9f; hi = -1e9f;
    }
}

// sampled t-range in 16-sample chunks; coords stay within clamp range
__device__ __forceinline__ int ray_chunks16(float x0, float y0, float ca, float sa,
                                            int& itlo) {
    float lo = -1e9f, hi = 1e9f;
    clip_axis2(x0, -sa, -2.0f, 257.0f, lo, hi);
    clip_axis2(y0,  ca, -2.0f, 257.0f, lo, hi);
    if (hi < lo) { itlo = 0; return 0; }
    int a = (int)floorf(lo + TOFF) - 1; if (a < 0) a = 0;
    int b = (int)ceilf(hi + TOFF) + 1;  if (b > NT - 1) b = NT - 1;
    itlo = a;
    if (b < a) return 0;
    return (b - a + 16) >> 4;
}

struct RaySetup {
    int angle, bin, ai, nc;
    float u, v, du, dv;
    bool useT;
};

__device__ __forceinline__ RaySetup ray_setup(int rr, int angleStart, int angleStride,
                                              const float* __restrict__ cosA,
                                              const float* __restrict__ sinA,
                                              int slane) {
    RaySetup R;
    R.ai = rr / NUMBIN;
    R.bin = rr - R.ai * NUMBIN;
    R.angle = angleStart + R.ai * angleStride;    // always < 180
    float ca = cosA[R.angle], sa = sinA[R.angle];
    float s = (float)R.bin - CDET;
    float x0 = fmaf(s, ca, CPIX);             // x(tt) = x0 - tt*sa
    float y0 = fmaf(s, sa, CPIX);             // y(tt) = y0 + tt*ca
    int itlo;
    R.nc = ray_chunks16(x0, y0, ca, sa, itlo);
    R.useT = fabsf(ca) > fabsf(sa);           // uniform per sub-group
    float u0 = R.useT ? y0 : x0, du = R.useT ? ca : -sa;   // fast (contiguous)
    float v0 = R.useT ? x0 : y0, dv = R.useT ? -sa : ca;   // slow (strided)
    float tt0 = (float)(itlo + slane) - TOFF;
    R.u = fmaf(tt0, du, u0);
    R.v = fmaf(tt0, dv, v0);
    R.du = du; R.dv = dv;
    return R;
}

// chunk loop unrolled x2, dual accumulators; DUAL also samples imgB at the
// same addresses (shared coord/addr math — the cold-branch image).
template <bool DUAL>
__device__ __forceinline__ void march(const float* __restrict__ imgA,
                                      const float* __restrict__ imgB,
                                      float u, float v, float du, float dv,
                                      int nc, float& outA, float& outB) {
    const float du16 = du * 16.0f, dv16 = dv * 16.0f;
    const float du32 = du * 32.0f, dv32 = dv * 32.0f;
    float a0 = 0.0f, a1 = 0.0f, b0 = 0.0f, b1 = 0.0f;
    int ic = 0;
    for (; ic + 1 < nc; ic += 2) {
        float u1 = fminf(fmaxf(u, -1.0f), 256.0f);
        float v1 = fminf(fmaxf(v, -1.0f), 256.0f);
        float u2 = fminf(fmaxf(u + du16, -1.0f), 256.0f);
        float v2 = fminf(fmaxf(v + dv16, -1.0f), 256.0f);
        float fu1 = floorf(u1), fv1 = floorf(v1);
        float fu2 = floorf(u2), fv2 = floorf(v2);
        float wu1 = u1 - fu1, wv1 = v1 - fv1;
        float wu2 = u2 - fu2, wv2 = v2 - fv2;
        int idx1 = (int)fmaf(fv1, (float)QW, fu1);
        int idx2 = (int)fmaf(fv2, (float)QW, fu2);
        f4q qa1 = *(const f4q*)(imgA + idx1 * 2);
        f4q qa2 = *(const f4q*)(imgA + idx2 * 2);
        float t1 = fmaf(wu1, qa1.z - qa1.x, qa1.x);
        float c1 = fmaf(wu1, qa1.w - qa1.y, qa1.y);
        a0 += fmaf(wv1, c1 - t1, t1);
        float t2 = fmaf(wu2, qa2.z - qa2.x, qa2.x);
        float c2 = fmaf(wu2, qa2.w - qa2.y, qa2.y);
        a1 += fmaf(wv2, c2 - t2, t2);
        if (DUAL) {
            f4q qb1 = *(const f4q*)(imgB + idx1 * 2);
            f4q qb2 = *(const f4q*)(imgB + idx2 * 2);
            float s1 = fmaf(wu1, qb1.z - qb1.x, qb1.x);
            float d1 = fmaf(wu1, qb1.w - qb1.y, qb1.y);
            b0 += fmaf(wv1, d1 - s1, s1);
            float s2 = fmaf(wu2, qb2.z - qb2.x, qb2.x);
            float d2 = fmaf(wu2, qb2.w - qb2.y, qb2.y);
            b1 += fmaf(wv2, d2 - s2, s2);
        }
        u += du32; v += dv32;
    }
    if (ic < nc) {
        float u1 = fminf(fmaxf(u, -1.0f), 256.0f);
        float v1 = fminf(fmaxf(v, -1.0f), 256.0f);
        float fu1 = floorf(u1), fv1 = floorf(v1);
        float wu1 = u1 - fu1, wv1 = v1 - fv1;
        int idx1 = (int)fmaf(fv1, (float)QW, fu1);
        f4q qa1 = *(const f4q*)(imgA + idx1 * 2);
        float t1 = fmaf(wu1, qa1.z - qa1.x, qa1.x);
        float c1 = fmaf(wu1, qa1.w - qa1.y, qa1.y);
        a0 += fmaf(wv1, c1 - t1, t1);
        if (DUAL) {
            f4q qb1 = *(const f4q*)(imgB + idx1 * 2);
            float s1 = fmaf(wu1, qb1.z - qb1.x, qb1.x);
            float d1 = fmaf(wu1, qb1.w - qb1.y, qb1.y);
            b0 += fmaf(wv1, d1 - s1, s1);
        }
    }
    outA = a0 + a1;
    outB = b0 + b1;
}

// ---------------- init + Minv in one dispatch ----------------
// Also builds the pristine f0 quads (Q0/QT0) used by the cold (res1<=thr)
// branch after select#1 was folded away.
__global__ __launch_bounds__(256)
void init_minv_kernel(float* __restrict__ cosA, float* __restrict__ sinA,
                      float* __restrict__ Qf, float* __restrict__ QTf,
                      float* __restrict__ Q0f, float* __restrict__ QT0f,
                      float* __restrict__ minv,
                      const float* __restrict__ f0) {
    int idx = blockIdx.x * blockDim.x + threadIdx.x;
    if (idx < NUMTHETA) {
        float th = (float)((double)idx * 0.017453292519943295);
        cosA[idx] = (float)cos((double)th);
        sinA[idx] = (float)sin((double)th);
    }
    if (idx < QN2) {
        int qr = idx / QW, qc = idx - qr * QW;
        int r = qr - 1, c = qc - 1;                 // r in [-1,256], c in [-1,258]
        bool cv = ((unsigned)c < 256u);
        bool rv0 = ((unsigned)r < 256u), rv1 = ((unsigned)(r + 1) < 256u);
        float a = (cv && rv0) ? f0[r * NUMPIX + c] : 0.0f;
        float b = (cv && rv1) ? f0[(r + 1) * NUMPIX + c] : 0.0f;
        Qf[idx * 2] = a;  Qf[idx * 2 + 1] = b;
        Q0f[idx * 2] = a; Q0f[idx * 2 + 1] = b;
        // transposed image: imgT(r,c) = f0[c][r]
        float ta = (cv && rv0) ? f0[c * NUMPIX + r] : 0.0f;
        float tb = (cv && rv1) ? f0[c * NUMPIX + (r + 1)] : 0.0f;
        QTf[idx * 2] = ta;  QTf[idx * 2 + 1] = tb;
        QT0f[idx * 2] = ta; QT0f[idx * 2 + 1] = tb;
    }

    // ---- Minv portion: 16 lanes per ray, 4 rays/wave, 16 rays/block.
    // Own per-ray trig via __sincosf (normalizer only; ~1e-6 rel, far under
    // threshold). Angles [0,180) only; mirror gets the identical value.
    const int lane = threadIdx.x & 63;
    const int wid = threadIdx.x >> 6;
    const int sub = lane >> 4, slane = lane & 15;
    int ray = blockIdx.x * 16 + wid * 4 + sub;
    if (ray >= NRAYS_HALF) return;           // whole 16-lane group exits
    int angle = ray / NUMBIN;                // angle in [0,180)
    int bin = ray - angle * NUMBIN;
    float th = (float)((double)angle * 0.017453292519943295);
    float ca, sa;
    __sincosf(th, &sa, &ca);
    float s = (float)bin - CDET;
    float x0 = fmaf(s, ca, CPIX);                 // x(tt) = x0 - tt*sa
    float y0 = fmaf(s, sa, CPIX);                 // y(tt) = y0 + tt*ca
    float acc = 0.0f;
    int count = 0;
    float lo = -1e9f, hi = 1e9f;
    clip_axis2(x0, -sa, -2.0f, 257.0f, lo, hi);
    clip_axis2(y0,  ca, -2.0f, 257.0f, lo, hi);
    int e1a = 0, e1b = -1, e2a = 0, e2b = -1;
    if (hi >= lo) {
        int itA = (int)floorf(lo + TOFF) - 1; if (itA < 0) itA = 0;
        int itB = (int)ceilf(hi + TOFF) + 1;  if (itB > NT - 1) itB = NT - 1;
        if (itB >= itA) {
            // strict interior: both coords in (0.05, 254.95) -> weight exactly 1
            float ilo = -1e9f, ihi = 1e9f;
            clip_axis2(x0, -sa, 0.05f, 254.95f, ilo, ihi);
            clip_axis2(y0,  ca, 0.05f, 254.95f, ilo, ihi);
            int jA = 1, jB = 0;
            if (ihi >= ilo) {
                jA = (int)ceilf(ilo + TOFF) + 1;
                jB = (int)floorf(ihi + TOFF) - 1;
                if (jA < itA) jA = itA;
                if (jB > itB) jB = itB;
            }
            if (jB >= jA) {
                count = jB - jA + 1;
                e1a = itA; e1b = jA - 1;
                e2a = jB + 1; e2b = itB;
            } else {
                e1a = itA; e1b = itB;       // no interior: one full edge loop
            }
        }
    }
    #pragma unroll 1
    for (int base = e1a; base <= e1b; base += 16) {
        int t = base + slane;
        float tt = (float)t - TOFF;
        float x = fmaf(-tt, sa, x0);
        float y = fmaf(tt, ca, y0);
        float fx = floorf(x), fy = floorf(y);
        float wx = x - fx, wy = y - fy;
        int c0 = (int)fx, r0 = (int)fy;
        float ux = (((unsigned)c0 < 256u) ? (1.0f - wx) : 0.0f) +
                   (((unsigned)(c0 + 1) < 256u) ? wx : 0.0f);
        float uy = (((unsigned)r0 < 256u) ? (1.0f - wy) : 0.0f) +
                   (((unsigned)(r0 + 1) < 256u) ? wy : 0.0f);
        if (t <= e1b) acc += ux * uy;
    }
    #pragma unroll 1
    for (int base = e2a; base <= e2b; base += 16) {
        int t = base + slane;
        float tt = (float)t - TOFF;
        float x = fmaf(-tt, sa, x0);
        float y = fmaf(tt, ca, y0);
        float fx = floorf(x), fy = floorf(y);
        float wx = x - fx, wy = y - fy;
        int c0 = (int)fx, r0 = (int)fy;
        float ux = (((unsigned)c0 < 256u) ? (1.0f - wx) : 0.0f) +
                   (((unsigned)(c0 + 1) < 256u) ? wx : 0.0f);
        float uy = (((unsigned)r0 < 256u) ? (1.0f - wy) : 0.0f) +
                   (((unsigned)(r0 + 1) < 256u) ? wy : 0.0f);
        if (t <= e2b) acc += ux * uy;
    }
    acc += __shfl_down(acc, 8, 16);
    acc += __shfl_down(acc, 4, 16);
    acc += __shfl_down(acc, 2, 16);
    acc += __shfl_down(acc, 1, 16);
    if (slane == 0) {
        float m = fmaxf(acc + (float)count, DEN_EPS);
        minv[angle * NUMBIN + bin] = m;
        minv[(angle + NANG_HALF) * NUMBIN + (NUMBIN - 1 - bin)] = m;
    }
}

// residual block-unit: marches 16 half-rays of fk, returns block partial of
// sum over (base + mirror) squared diffs. All threads return the total.
__device__ __forceinline__ float res_block_partial(
        int unit, const float* __restrict__ Qn, const float* __restrict__ Qt,
        const float* __restrict__ sino,
        const float* __restrict__ cosA, const float* __restrict__ sinA,
        float* partLds) {
    const int wid = threadIdx.x >> 6, lane = threadIdx.x & 63;
    const int sub = lane >> 4, slane = lane & 15;
    int ray = unit * 16 + wid * 4 + sub;
    bool valid = ray < NRAYS_HALF;
    int rr = valid ? ray : NRAYS_HALF - 1;
    RaySetup R = ray_setup(rr, 0, 1, cosA, sinA, slane);
    const float* img = (R.useT ? Qt : Qn) + (QW + 1) * 2;
    float acc, dum;
    march<false>(img, img, R.u, R.v, R.du, R.dv, valid ? R.nc : 0, acc, dum);
    acc += __shfl_down(acc, 8, 16);
    acc += __shfl_down(acc, 4, 16);
    acc += __shfl_down(acc, 2, 16);
    acc += __shfl_down(acc, 1, 16);
    float d2 = 0.0f;
    if (slane == 0 && valid) {
        float d = acc - sino[R.angle * NUMBIN + R.bin];
        int a2 = R.angle + NANG_HALF;
        int b2 = NUMBIN - 1 - R.bin;
        float dm = acc - sino[a2 * NUMBIN + b2];
        d2 = d * d + dm * dm;
    }
    d2 += __shfl_down(d2, 16);
    d2 += __shfl_down(d2, 32);
    if (lane == 0) partLds[wid] = d2;
    __syncthreads();
    return partLds[0] + partLds[1] + partLds[2] + partLds[3];
}

// ---------------- subset forward projection (diffs) ----------------
__global__ __launch_bounds__(256)
void fp_sub_kernel(const float* __restrict__ Qn, const float* __restrict__ Qt,
                   const float* __restrict__ sino, const float* __restrict__ minv,
                   float* __restrict__ gOut,
                   const float* __restrict__ cosA, const float* __restrict__ sinA,
                   int j) {
    const int wid = threadIdx.x >> 6, lane = threadIdx.x & 63;
    const int sub = lane >> 4, slane = lane & 15;
    int ray = blockIdx.x * 16 + wid * 4 + sub;
    bool valid = ray < NRAYS_SUBH;
    int rr = valid ? ray : NRAYS_SUBH - 1;
    RaySetup R = ray_setup(rr, j, NS, cosA, sinA, slane);
    const float* img = (R.useT ? Qt : Qn) + (QW + 1) * 2;
    float acc, dum;
    march<false>(img, img, R.u, R.v, R.du, R.dv, valid ? R.nc : 0, acc, dum);
    acc += __shfl_down(acc, 8, 16);
    acc += __shfl_down(acc, 4, 16);
    acc += __shfl_down(acc, 2, 16);
    acc += __shfl_down(acc, 1, 16);
    if (slane == 0 && valid) {
        gOut[R.ai * NUMBIN + R.bin] =
            (sino[R.angle * NUMBIN + R.bin] - acc) /
            minv[R.angle * NUMBIN + R.bin];
        int a2 = R.angle + NANG_HALF;
        int b2 = NUMBIN - 1 - R.bin;
        gOut[(R.ai + NANG_SUBH) * NUMBIN + b2] =
            (sino[a2 * NUMBIN + b2] - acc) /
            minv[a2 * NUMBIN + b2];
    }
}

// ---------------- merged: residual(fk1) partials + subset-0 dual FP ------
// Both parts read the same image state (fk1); independent of each other, so
// one dispatch saves a boundary. Residual blocks write DISTINCT partial
// slots (plain store — no atomics, see ROUND-2/3 LESSON). Subset part
// marches Qf AND Q0 (shared addresses) and writes both diff variants;
// bp(iter2,j=0) reduces the partials and picks by res1.
__global__ __launch_bounds__(256)
void fp_merged_kernel(const float* __restrict__ Qn, const float* __restrict__ Qt,
                      const float* __restrict__ Q0n, const float* __restrict__ Q0t,
                      const float* __restrict__ sino, const float* __restrict__ minv,
                      float* __restrict__ gA, float* __restrict__ gB,
                      const float* __restrict__ cosA, const float* __restrict__ sinA,
                      float* __restrict__ resP1) {
    __shared__ float part[4];
    int bid = blockIdx.x;
    if (bid < HALF_BLOCKS) {
        float tot = res_block_partial(bid, Qn, Qt, sino, cosA, sinA, part);
        if (threadIdx.x == 0) resP1[bid] = tot;
        return;
    }
    int bid2 = bid - HALF_BLOCKS;
    const int wid = threadIdx.x >> 6, lane = threadIdx.x & 63;
    const int sub = lane >> 4, slane = lane & 15;
    int ray = bid2 * 16 + wid * 4 + sub;
    bool valid = ray < NRAYS_SUBH;
    int rr = valid ? ray : NRAYS_SUBH - 1;
    RaySetup R = ray_setup(rr, 0, NS, cosA, sinA, slane);   // j = 0
    const float* imgA = (R.useT ? Qt : Qn) + (QW + 1) * 2;
    const float* imgB = (R.useT ? Q0t : Q0n) + (QW + 1) * 2;
    float accA, accB;
    march<true>(imgA, imgB, R.u, R.v, R.du, R.dv, valid ? R.nc : 0, accA, accB);
    accA += __shfl_down(accA, 8, 16);
    accB += __shfl_down(accB, 8, 16);
    accA += __shfl_down(accA, 4, 16);
    accB += __shfl_down(accB, 4, 16);
    accA += __shfl_down(accA, 2, 16);
    accB += __shfl_down(accB, 2, 16);
    accA += __shfl_down(accA, 1, 16);
    accB += __shfl_down(accB, 1, 16);
    if (slane == 0 && valid) {
        float m1 = minv[R.angle * NUMBIN + R.bin];
        float s1 = sino[R.angle * NUMBIN + R.bin];
        gA[R.ai * NUMBIN + R.bin] = (s1 - accA) / m1;
        gB[R.ai * NUMBIN + R.bin] = (s1 - accB) / m1;
        int a2 = R.angle + NANG_HALF;
        int b2 = NUMBIN - 1 - R.bin;
        float m2 = minv[a2 * NUMBIN + b2];
        float s2 = sino[a2 * NUMBIN + b2];
        gA[(R.ai + NANG_SUBH) * NUMBIN + b2] = (s2 - accA) / m2;
        gB[(R.ai + NANG_SUBH) * NUMBIN + b2] = (s2 - accB) / m2;
    }
}

// ---------------- residual(fk2): partials only (no atomics) ----------------
__global__ __launch_bounds__(256)
void fp_res2_kernel(const float* __restrict__ Qn, const float* __restrict__ Qt,
                    const float* __restrict__ sino,
                    const float* __restrict__ cosA, const float* __restrict__ sinA,
                    float* __restrict__ resP2) {
    __shared__ float part[4];
    float tot = res_block_partial(blockIdx.x, Qn, Qt, sino, cosA, sinA, part);
    if (threadIdx.x == 0) resP2[blockIdx.x] = tot;
}

// ---------------- select: reduce both partial arrays + write output ------
// f2 = res2>thr ? fk2 : (res1>thr ? fk1 : f0). fcur holds fk1 (written by
// bp(iter1,j=3)); fk2 is Qf canonical. Each block redundantly reduces the
// 2x4129 partials (~33 KB from L2/L3 — cheap, fully parallel).
__global__ __launch_bounds__(256)
void select_kernel(float* __restrict__ fcur,
                   const float* __restrict__ Qn, const float* __restrict__ f0,
                   const float* __restrict__ resP1,
                   const float* __restrict__ resP2) {
    __shared__ float b1[4], b2[4];
    const int tid = threadIdx.x;
    float a1 = 0.0f, a2 = 0.0f;
    for (int i = tid; i < HALF_BLOCKS; i += 256) {
        a1 += resP1[i];
        a2 += resP2[i];
    }
    #pragma unroll
    for (int off = 32; off; off >>= 1) {
        a1 += __shfl_down(a1, off);
        a2 += __shfl_down(a2, off);
    }
    if ((tid & 63) == 0) { b1[tid >> 6] = a1; b2[tid >> 6] = a2; }
    __syncthreads();
    bool upd1 = (b1[0] + b1[1] + b1[2] + b1[3]) > RES2_THRESH;
    bool upd2 = (b2[0] + b2[1] + b2[2] + b2[3]) > RES2_THRESH;
    int p = blockIdx.x * 256 + tid;
    int px = p & (NUMPIX - 1), py = p >> 8;
    float v = upd2 ? Qn[((py + 1) * QW + (px + 1)) * 2]
                   : (upd1 ? fcur[p] : f0[p]);
    fcur[p] = v;
}

// ---------------- backprojection + SART update ----------------
// Mirror-paired: angles a and a+180 share the sd chain (sd2 = 366 - sd;
// value2 = w*g2[365-i0] + (1-w)*g2[366-i0]; i0 in [2,363] so in-bounds).
// chooseFlag: reduce resP1 and pick {gA,Qf} vs {gB,Q0f} by res1 (cold
// branch of folded select#1). chooseFlag is grid-uniform, so the embedded
// __syncthreads is safe.
__global__ __launch_bounds__(256)
void bp_update_kernel(float* __restrict__ Qf, float* __restrict__ QTf,
                      const float* __restrict__ Q0f,
                      const float* __restrict__ gA, const float* __restrict__ gB,
                      const float* __restrict__ cosA, const float* __restrict__ sinA,
                      const float* __restrict__ resP1, float* __restrict__ fcur,
                      int j, int doClamp, int writeFcur, int chooseFlag) {
    __shared__ float part[4][64];
    const float* g = gA;
    const float* src = Qf;
    if (chooseFlag) {
        __shared__ float rbuf[4];
        float a = 0.0f;
        for (int i = threadIdx.x; i < HALF_BLOCKS; i += 256) a += resP1[i];
        #pragma unroll
        for (int off = 32; off; off >>= 1) a += __shfl_down(a, off);
        if ((threadIdx.x & 63) == 0) rbuf[threadIdx.x >> 6] = a;
        __syncthreads();
        float r1v = rbuf[0] + rbuf[1] + rbuf[2] + rbuf[3];
        if (!(r1v > RES2_THRESH)) { g = gB; src = Q0f; }
    }
    const int tx = threadIdx.x & 63;
    const int ty = threadIdx.x >> 6;
    int p = blockIdx.x * 64 + tx;
    int px = p & (NUMPIX - 1), py = p >> 8;
    float X = (float)px - CPIX, Y = (float)py - CPIX;
    float acc = 0.0f;
    for (int i = ty; i < NANG_SUBH; i += 4) {
        int angle = j + NS * i;
        float ca = cosA[angle], sa = sinA[angle];
        float sd = fmaf(X, ca, fmaf(Y, sa, CDET));   // always in [2.7, 363.3]
        float fl = floorf(sd);
        float w = sd - fl;
        int i0 = (int)fl;
        f2u gv = *(const f2u*)(g + i * NUMBIN + i0);
        acc += fmaf(w, gv.y - gv.x, gv.x);
        // mirror angle (a+180): sd2 = 366 - sd
        f2u gw = *(const f2u*)(g + (i + NANG_SUBH) * NUMBIN + (365 - i0));
        acc += fmaf(w, gw.x - gw.y, gw.y);
    }
    part[ty][tx] = acc;
    __syncthreads();
    if (ty == 0) {
        float s = part[0][tx] + part[1][tx] + part[2][tx] + part[3][tx];
        float bp = (fabsf(s) > 1000.0f) ? 0.0f : s;
        float v = src[((py + 1) * QW + (px + 1)) * 2] + bp * INV_DINV;
        if (doClamp) v = fmaxf(v, EPS_F);
        // quad-image updates: pixel (py,px) lives in 2 elements per layout
        Qf[((py + 1) * QW + (px + 1)) * 2]      = v;
        Qf[(py * QW + (px + 1)) * 2 + 1]        = v;
        QTf[((px + 1) * QW + (py + 1)) * 2]     = v;
        QTf[(px * QW + (py + 1)) * 2 + 1]       = v;
        if (writeFcur) fcur[p] = v;               // fk1 snapshot (hot-path f1)
    }
}

extern "C" void kernel_launch(void* const* d_in, const int* in_sizes, int n_in,
                              void* d_out, int out_size, void* d_ws, size_t ws_size,
                              hipStream_t stream) {
    const float* f0 = (const float*)d_in[0];     // [256,256]
    const float* sino = (const float*)d_in[1];   // [360,367]
    float* fcur = (float*)d_out;                 // [256,256] output "f"
    float* ws = (float*)d_ws;

    float* cosA = ws + OFF_COS;
    float* sinA = ws + OFF_SIN;
    float* minv = ws + OFF_MINV;   // [360,367] indexed by global angle
    float* resP1 = ws + OFF_RESP1; // residual-1 block partials [4129]
    float* resP2 = ws + OFF_RESP2; // residual-2 block partials [4129]
    float* Qf   = ws + OFF_Q;      // quad image (normal) — canonical fk store
    float* QTf  = ws + OFF_QT;     // quad image (transposed)
    float* Q0f  = ws + OFF_Q0;     // pristine f0 quads (cold branch)
    float* QT0f = ws + OFF_QT0;
    float* dfA  = ws + OFF_DIFF;   // diffs from fk
    float* dfB  = ws + OFF_DIFFB;  // diffs from f0 (cold branch)

    // 19 dispatches: select#1 folded into bp via resP1 reduce; residual#1
    // merged with fp(iter2,j=0). All cross-block reductions are
    // distinct-slot partials + consumer reduce — zero device atomics.
    init_minv_kernel<<<HALF_BLOCKS, 256, 0, stream>>>(
        cosA, sinA, Qf, QTf, Q0f, QT0f, minv, f0);

    // ---- iteration 1 ----
    for (int j = 0; j < NS; j++) {
        fp_sub_kernel<<<SUBH_BLOCKS, 256, 0, stream>>>(
            Qf, QTf, sino, minv, dfA, cosA, sinA, j);
        bp_update_kernel<<<NPIX2 / 64, 256, 0, stream>>>(
            Qf, QTf, Q0f, dfA, dfB, cosA, sinA, resP1, fcur,
            j, (j == NS - 1) ? 1 : 0, (j == NS - 1) ? 1 : 0, 0);
    }
    // ---- iteration boundary: residual(fk1) partials + subset-0 dual FP ----
    fp_merged_kernel<<<HALF_BLOCKS + SUBH_BLOCKS, 256, 0, stream>>>(
        Qf, QTf, Q0f, QT0f, sino, minv, dfA, dfB, cosA, sinA, resP1);
    bp_update_kernel<<<NPIX2 / 64, 256, 0, stream>>>(
        Qf, QTf, Q0f, dfA, dfB, cosA, sinA, resP1, fcur,
        0, 0, 0, 1);
    // ---- iteration 2, subsets 1..3 ----
    for (int j = 1; j < NS; j++) {
        fp_sub_kernel<<<SUBH_BLOCKS, 256, 0, stream>>>(
            Qf, QTf, sino, minv, dfA, cosA, sinA, j);
        bp_update_kernel<<<NPIX2 / 64, 256, 0, stream>>>(
            Qf, QTf, Q0f, dfA, dfB, cosA, sinA, resP1, fcur,
            j, (j == NS - 1) ? 1 : 0, 0, 0);
    }
    // ---- final residual partials + select ----
    fp_res2_kernel<<<HALF_BLOCKS, 256, 0, stream>>>(
        Qf, QTf, sino, cosA, sinA, resP2);
    select_kernel<<<NPIX2 / 256, 256, 0, stream>>>(
        fcur, Qf, f0, resP1, resP2);
}